// Round 11
// baseline (38.293 us; speedup 1.0000x reference)
//
#include <hip/hip_runtime.h>
#include <math.h>

#define BB 32
#define TT 2048
#define CC 128
#define EE 256
#define LL 512
#define TYY 128
#define PP 24
#define NSTR 512        // streaming blocks: 32 b x 16 chunks (128 t each)
#define NSIN 256        // sin-pool blocks: 32 b x 8 chunks (256 t each)

// ws layout (floats):
//   pbuf  : [NSTR][2][P][64][2] = 3145728  at 0        (float2 cells: sum,cnt)
//   tpart : [B*8][E]            = 65536    at 3145728
//   cbase : [B][P][C]           = 98304    at 3211264
//   cemean: [E]                 = 256      at 3309568
#define WS_PBUF  0
#define WS_TPART 3145728
#define WS_CBASE 3211264
#define WS_CEM   3309568

// ---------------------------------------------------------------------------
// K1: heterogeneous launch, 768 blocks x 256 threads, ZERO in-loop barriers.
//  blocks [0,512): phase-bucket masked sum/count via wave-private LDS RMW.
//    Block (b, chunk of 128 t). Wave w: chalf=w&1 (c = chalf*64+lane),
//    thalf=w>>1 (64 t's). Each wave owns acc[w][P][64] float2 cells —
//    lane-exclusive -> non-atomic RMW race-free; waves fully independent,
//    ONE __syncthreads before the cross-wave flush.
//  blocks [512,768): sin-pool (pure VALU) — runs concurrently on the same
//    CUs, overlapping the memory stream (MFMA/VALU/mem pipes co-schedule).
// ---------------------------------------------------------------------------
__global__ __launch_bounds__(256) void k_main(const float* __restrict__ ts,
                                              const float* __restrict__ X,
                                              const int*   __restrict__ M,
                                              const float* __restrict__ tw,
                                              const float* __restrict__ tbias,
                                              float* __restrict__ pbuf,
                                              float* __restrict__ tpart) {
    __shared__ float acc[4][PP * 64 * 2];   // 48 KB, wave-private quarters
    __shared__ float s_ts[256];
    const int tid = threadIdx.x;
    const int blk = blockIdx.x;

    if (blk >= NSTR) {
        // ---- sin-pool block: (b, chunk of 256 t) ----
        const int sb = blk - NSTR;
        const int b = sb >> 3;
        const int chunk = sb & 7;
        s_ts[tid] = ts[b * TT + chunk * 256 + tid];
        __syncthreads();
        const float w = tw[tid];
        const float bb = tbias[tid];
        float a = 0.0f;
#pragma unroll 16
        for (int j = 0; j < 256; ++j) {
            const float v = fmaf(s_ts[j], w, bb);
            a += v + __sinf(v);
        }
        tpart[sb * EE + tid] = a;
        return;
    }

    // ---- streaming block: (b, chunk of 128 t) ----
    const int b = blk >> 4;
    const int chunk = blk & 15;
    const int wave = tid >> 6;
    const int lane = tid & 63;
    const int chalf = wave & 1;
    const int thalf = wave >> 1;
    const int tB = chunk * 128 + thalf * 64;
    const long cg = (long)(chalf * 64 + lane);

    // zero own quarter (wave-private: no barrier needed before use)
    {
        float2* az = (float2*)acc[wave];
#pragma unroll
        for (int i = lane; i < PP * 64; i += 64) az[i] = make_float2(0.0f, 0.0f);
    }

    float2* aw = (float2*)acc[wave];
    for (int g = 0; g < 8; ++g) {
        float xv[8]; int mv[8]; float tv[8];
#pragma unroll
        for (int k = 0; k < 8; ++k) {
            const int t = tB + g * 8 + k;
            const long r0 = ((long)(b * TT + t)) * CC + cg;
            xv[k] = X[r0];
            mv[k] = M[r0];
            tv[k] = ts[b * TT + t];               // wave-uniform scalar load
        }
#pragma unroll
        for (int k = 0; k < 8; ++k) {
            const int p = ((int)floorf(tv[k])) % PP;   // ts >= 0
            const float m = (float)mv[k];
            float2 cell = aw[p * 64 + lane];
            cell.x += xv[k] * m;
            cell.y += m;
            aw[p * 64 + lane] = cell;
        }
    }
    __syncthreads();

    // flush: sum the two t-half waves per channel-half -> per-block partials
    float2* pb2 = (float2*)(pbuf + (long)blk * (2 * PP * 64 * 2));
#pragma unroll
    for (int ch = 0; ch < 2; ++ch) {
        const float2* a0 = (const float2*)acc[ch];
        const float2* a1 = (const float2*)acc[ch + 2];
        for (int i = tid; i < PP * 64; i += 256) {
            const float2 u = a0[i];
            const float2 v = a1[i];
            pb2[ch * (PP * 64) + i] = make_float2(u.x + v.x, u.y + v.y);
        }
    }
}

// ---------------------------------------------------------------------------
// K2: reduce chunk partials -> c_base; 2 extra blocks compute ce col-mean.
// grid = B*P + 2 (770), block = 128
// ---------------------------------------------------------------------------
__global__ __launch_bounds__(128) void k_reduce(const float* __restrict__ pbuf,
                                                float* __restrict__ cbase,
                                                const float* __restrict__ ce,
                                                float* __restrict__ cemean) {
    const int blk = blockIdx.x;
    if (blk >= BB * PP) {
        const int e = (blk - BB * PP) * 128 + threadIdx.x;
        float s = 0.0f;
#pragma unroll 16
        for (int c = 0; c < CC; ++c) s += ce[c * EE + e];
        cemean[e] = s * (1.0f / CC);
        return;
    }
    const int b = blk / PP;
    const int p = blk % PP;
    const int c = threadIdx.x;
    const int ch = c >> 6;
    const int cl = c & 63;
    float s = 0.0f, n = 0.0f;
#pragma unroll
    for (int k = 0; k < 16; ++k) {
        const float2 v = *(const float2*)(pbuf
            + ((long)(b * 16 + k)) * (2 * PP * 64 * 2)
            + (ch * PP * 64 + p * 64 + cl) * 2);
        s += v.x;
        n += v.y;
    }
    cbase[(b * PP + p) * CC + c] = s / fmaxf(n, 1.0f);
}

// ---------------------------------------------------------------------------
// K3: decoder MLP + output scatter. grid = B (32), block = 1024.
// ---------------------------------------------------------------------------
__global__ __launch_bounds__(1024) void k_tail(const float* __restrict__ tpart,
                                               const float* __restrict__ cemean,
                                               const float* __restrict__ w1,
                                               const float* __restrict__ b1,
                                               const float* __restrict__ w2,
                                               const float* __restrict__ b2,
                                               const float* __restrict__ cbase,
                                               const float* __restrict__ yt,
                                               float* __restrict__ out) {
    __shared__ float s_pool[EE];
    __shared__ float s_h[LL];
    __shared__ float s_part[1024];
    __shared__ float s_cb[PP * CC];
    __shared__ float s_y[CC];
    const int b = blockIdx.x;
    const int tid = threadIdx.x;

    for (int i = tid; i < PP * CC; i += 1024) s_cb[i] = cbase[b * PP * CC + i];

    if (tid < EE) {
        float sp = 0.0f;
#pragma unroll
        for (int k = 0; k < 8; ++k) sp += tpart[(b * 8 + k) * EE + tid];
        s_pool[tid] = sp * (1.0f / TT) + cemean[tid];
    }
    __syncthreads();

    {
        const int l = tid & 511;
        const int hh = tid >> 9;
        float ha = 0.0f;
#pragma unroll 16
        for (int e = hh * 128; e < hh * 128 + 128; ++e)
            ha = fmaf(s_pool[e], w1[e * LL + l], ha);
        s_part[tid] = ha;
    }
    __syncthreads();
    if (tid < LL)
        s_h[tid] = fmaxf(b1[tid] + s_part[tid] + s_part[tid + 512], 0.0f);
    __syncthreads();

    {
        const int c = tid & 127;
        const int q8 = tid >> 7;
        float y = 0.0f;
#pragma unroll 16
        for (int l = q8 * 64; l < q8 * 64 + 64; ++l)
            y = fmaf(s_h[l], w2[l * CC + c], y);
        s_part[tid] = y;
    }
    __syncthreads();
    if (tid < CC) {
        float y = b2[tid];
#pragma unroll
        for (int i = 0; i < 8; ++i) y += s_part[tid + 128 * i];
        s_y[tid] = y;
    }
    __syncthreads();

    for (int i = tid; i < TYY * CC; i += 1024) {
        const int ty = i >> 7;
        const int c = i & 127;
        const float v = yt[b * TYY + ty];
        int p = ((int)floorf(v)) % PP; if (p < 0) p += PP;
        out[((long)(b * TYY + ty)) * CC + c] = s_y[c] + s_cb[p * CC + c];
    }
}

extern "C" void kernel_launch(void* const* d_in, const int* in_sizes, int n_in,
                              void* d_out, int out_size, void* d_ws, size_t ws_size,
                              hipStream_t stream) {
    const float* ts   = (const float*)d_in[0];
    const float* X    = (const float*)d_in[1];
    const int*   M    = (const int*)  d_in[2];
    const float* yt   = (const float*)d_in[3];
    const float* tw   = (const float*)d_in[4];
    const float* tb   = (const float*)d_in[5];
    const float* ce   = (const float*)d_in[6];
    const float* w1   = (const float*)d_in[7];
    const float* b1   = (const float*)d_in[8];
    const float* w2   = (const float*)d_in[9];
    const float* b2   = (const float*)d_in[10];
    float* out = (float*)d_out;

    float* ws     = (float*)d_ws;
    float* pbuf   = ws + WS_PBUF;
    float* tpart  = ws + WS_TPART;
    float* cbase  = ws + WS_CBASE;
    float* cemean = ws + WS_CEM;

    k_main<<<NSTR + NSIN, 256, 0, stream>>>(ts, X, M, tw, tb, pbuf, tpart);
    k_reduce<<<BB * PP + 2, 128, 0, stream>>>(pbuf, cbase, ce, cemean);
    k_tail<<<BB, 1024, 0, stream>>>(tpart, cemean, w1, b1, w2, b2, cbase, yt, out);
}